// Round 5
// baseline (865.886 us; speedup 1.0000x reference)
//
#include <hip/hip_runtime.h>
#include <hip/hip_bf16.h>
#include <stdint.h>

// ---------------------------------------------------------------------------
// HeteroTextGCN round 5:
//  - gather: 16 lanes x 16B per row, 4 rows per wave-load instruction
//    (4x fewer VMEM instr/edge, 2x rows in flight); shfl_xor epilogue
//  - GEMM: s_out row-scale moved from staging loop to fp32 epilogue
//  - hist (8 per-XCD copies), CSR build unchanged
// ---------------------------------------------------------------------------

typedef __attribute__((ext_vector_type(8))) short bf16x8;
typedef __attribute__((ext_vector_type(4))) float f32x4;
typedef unsigned short u16;

#define SCAN_T 256
#define SCAN_E 8
#define SCAN_BLK (SCAN_T * SCAN_E)

__global__ __launch_bounds__(256)
void hist_kernel(const int* __restrict__ src, const int* __restrict__ dst,
                 int* __restrict__ cnt_out8, int* __restrict__ cnt_in8,
                 int E, int N) {
    int e = blockIdx.x * blockDim.x + threadIdx.x;
    int r = blockIdx.y;
    if (e >= E) return;
    int copy = blockIdx.x & 7;
    size_t base = ((size_t)copy * 3 + r) * N;
    atomicAdd(cnt_out8 + base + src[(size_t)r * E + e], 1);
    atomicAdd(cnt_in8  + base + dst[(size_t)r * E + e], 1);
}

__global__ __launch_bounds__(256)
void reduce_scales_kernel(const int* __restrict__ cnt_out8, const int* __restrict__ cnt_in8,
                          float* __restrict__ s_out, float* __restrict__ s_in,
                          int* __restrict__ cnt_in, int total /*3N*/) {
    int i = blockIdx.x * blockDim.x + threadIdx.x;
    if (i >= total) return;
    int co = 0, ci = 0;
#pragma unroll
    for (int c = 0; c < 8; c++) {
        co += cnt_out8[(size_t)c * total + i];
        ci += cnt_in8[(size_t)c * total + i];
    }
    s_out[i] = rsqrtf(fmaxf((float)co, 1.0f));
    s_in[i]  = rsqrtf(fmaxf((float)ci, 1.0f));
    cnt_in[i] = ci;
}

__global__ __launch_bounds__(SCAN_T)
void scan1_kernel(const int* __restrict__ cnt, int* __restrict__ pre,
                  int* __restrict__ bsums, int N) {
    int r = blockIdx.y, b = blockIdx.x, t = threadIdx.x;
    int base = b * SCAN_BLK + t * SCAN_E;
    int v[SCAN_E], s = 0;
#pragma unroll
    for (int j = 0; j < SCAN_E; j++) {
        int idx = base + j;
        v[j] = (idx < N) ? cnt[(size_t)r * N + idx] : 0;
        s += v[j];
    }
    __shared__ int sd[SCAN_T];
    sd[t] = s;
    __syncthreads();
    for (int off = 1; off < SCAN_T; off <<= 1) {
        int x = (t >= off) ? sd[t - off] : 0;
        __syncthreads();
        sd[t] += x;
        __syncthreads();
    }
    if (t == SCAN_T - 1) bsums[r * gridDim.x + b] = sd[t];
    int run = sd[t] - s;
#pragma unroll
    for (int j = 0; j < SCAN_E; j++) {
        int idx = base + j;
        if (idx < N) pre[(size_t)r * (N + 1) + idx] = run;
        run += v[j];
    }
}

__global__ void scan2_kernel(int* __restrict__ bsums, int* __restrict__ row_start,
                             int nb, int N) {
    for (int r = 0; r < 3; r++) {
        int run = 0;
        for (int b = 0; b < nb; b++) {
            int t = bsums[r * nb + b];
            bsums[r * nb + b] = run;
            run += t;
        }
        row_start[(size_t)r * (N + 1) + N] = run;
    }
}

__global__ __launch_bounds__(SCAN_T)
void scan3_kernel(int* __restrict__ pre, const int* __restrict__ bsums,
                  int* __restrict__ cursor, int nb, int N) {
    int r = blockIdx.y, b = blockIdx.x, t = threadIdx.x;
    int add = bsums[r * nb + b];
    int base = b * SCAN_BLK + t * SCAN_E;
#pragma unroll
    for (int j = 0; j < SCAN_E; j++) {
        int idx = base + j;
        if (idx < N) {
            int val = pre[(size_t)r * (N + 1) + idx] + add;
            pre[(size_t)r * (N + 1) + idx] = val;
            cursor[(size_t)r * N + idx] = val;
        }
    }
}

__global__ __launch_bounds__(256)
void bucket_fill_kernel(const int* __restrict__ src, const int* __restrict__ dst,
                        int* __restrict__ cursor, int* __restrict__ esrc,
                        int E, int N) {
    int e = blockIdx.x * blockDim.x + threadIdx.x;
    int r = blockIdx.y;
    if (e >= E) return;
    int d = dst[(size_t)r * E + e];
    int pos = atomicAdd(cursor + (size_t)r * N + d, 1);
    esrc[(size_t)r * E + pos] = src[(size_t)r * E + e];
}

// --- pre-split W0/W1 into hi/lo bf16, transposed to [r][n][k] --------------
__global__ __launch_bounds__(256)
void prep_w_kernel(const float* __restrict__ W0, const float* __restrict__ W1,
                   u16* __restrict__ w0hi, u16* __restrict__ w0lo,
                   u16* __restrict__ w1hi, u16* __restrict__ w1lo) {
    int idx = blockIdx.x * blockDim.x + threadIdx.x;
    const int n0 = 3 * 256 * 128;
    const int n1 = 3 * 128 * 128;
    if (idx >= n0 + n1) return;
    float f;
    u16 *phi, *plo;
    int oidx;
    if (idx < n0) {
        int r = idx / 32768, rem = idx % 32768;
        int n = rem / 256, k = rem % 256;
        f = W0[(size_t)r * 32768 + (size_t)k * 128 + n];
        phi = w0hi; plo = w0lo; oidx = idx;
    } else {
        int i2 = idx - n0;
        int r = i2 / 16384, rem = i2 % 16384;
        int n = rem / 128, k = rem % 128;
        f = W1[(size_t)r * 16384 + (size_t)k * 128 + n];
        phi = w1hi; plo = w1lo; oidx = i2;
    }
    uint32_t u = __float_as_uint(f);
    phi[oidx] = (u16)(u >> 16);
    float lo = f - __uint_as_float(u & 0xFFFF0000u);
    uint32_t ul = __float_as_uint(lo);
    plo[oidx] = (u16)((ul + 0x7FFFu + ((ul >> 16) & 1u)) >> 16);
}

// --- C_r[M x 128](bf16) = round_bf16(diag(s_r) * (A @ W_r)), r = blockIdx.y
__global__ __launch_bounds__(256)
void gemm_split_bf16(const float* __restrict__ A, const float* __restrict__ s_out,
                     const u16* __restrict__ Whi_all, const u16* __restrict__ Wlo_all,
                     u16* __restrict__ Cout_all, int M, int K, int Nn) {
    const int r = blockIdx.y;
    const float* scale = s_out + (size_t)r * Nn;
    const u16* Whi = Whi_all + (size_t)r * K * 128;
    const u16* Wlo = Wlo_all + (size_t)r * K * 128;
    u16* Cout = Cout_all + (size_t)r * Nn * 128;

    __shared__ u16 As_hi[128][40];
    __shared__ u16 As_lo[128][40];
    __shared__ u16 Bs_hi[128][40];
    __shared__ u16 Bs_lo[128][40];

    const int tid  = threadIdx.x;
    const int m0   = blockIdx.x * 128;
    const int lane = tid & 63;
    const int wave = tid >> 6;
    const int wm   = (wave & 1) * 64;
    const int wn   = (wave >> 1) * 64;
    const int lm   = lane & 15;
    const int kq   = (lane >> 4) * 8;

    f32x4 acc[4][4];
#pragma unroll
    for (int i = 0; i < 4; i++)
#pragma unroll
        for (int j = 0; j < 4; j++) acc[i][j] = (f32x4){0.f, 0.f, 0.f, 0.f};

    const int srow = tid >> 1;
    const int skb  = (tid & 1) * 16;

    const bool valid = (m0 + srow) < M;
    const float* arow = A + (size_t)(m0 + srow) * K;
    const u16* whrow = Whi + (size_t)srow * K;
    const u16* wlrow = Wlo + (size_t)srow * K;

    for (int k0 = 0; k0 < K; k0 += 32) {
        float fa[16];
        if (valid) {
            *(float4*)&fa[0]  = *(const float4*)(arow + k0 + skb);
            *(float4*)&fa[4]  = *(const float4*)(arow + k0 + skb + 4);
            *(float4*)&fa[8]  = *(const float4*)(arow + k0 + skb + 8);
            *(float4*)&fa[12] = *(const float4*)(arow + k0 + skb + 12);
        } else {
#pragma unroll
            for (int i = 0; i < 16; i++) fa[i] = 0.f;
        }
        uint32_t ah[8], al[8];
#pragma unroll
        for (int p = 0; p < 8; p++) {
            float f0 = fa[2 * p], f1 = fa[2 * p + 1];
            uint32_t u0 = __float_as_uint(f0), u1 = __float_as_uint(f1);
            ah[p] = (u0 >> 16) | (u1 & 0xFFFF0000u);
            float l0 = f0 - __uint_as_float(u0 & 0xFFFF0000u);
            float l1 = f1 - __uint_as_float(u1 & 0xFFFF0000u);
            al[p] = (__float_as_uint(l0) >> 16) | (__float_as_uint(l1) & 0xFFFF0000u);
        }
        *(uint4*)&As_hi[srow][skb]     = *(uint4*)&ah[0];
        *(uint4*)&As_hi[srow][skb + 8] = *(uint4*)&ah[4];
        *(uint4*)&As_lo[srow][skb]     = *(uint4*)&al[0];
        *(uint4*)&As_lo[srow][skb + 8] = *(uint4*)&al[4];

        *(uint4*)&Bs_hi[srow][skb]     = *(const uint4*)(whrow + k0 + skb);
        *(uint4*)&Bs_hi[srow][skb + 8] = *(const uint4*)(whrow + k0 + skb + 8);
        *(uint4*)&Bs_lo[srow][skb]     = *(const uint4*)(wlrow + k0 + skb);
        *(uint4*)&Bs_lo[srow][skb + 8] = *(const uint4*)(wlrow + k0 + skb + 8);

        __syncthreads();

        bf16x8 a_hi[4], a_lo[4], b_hi[4], b_lo[4];
#pragma unroll
        for (int i = 0; i < 4; i++) {
            a_hi[i] = *(const bf16x8*)&As_hi[wm + i * 16 + lm][kq];
            a_lo[i] = *(const bf16x8*)&As_lo[wm + i * 16 + lm][kq];
            b_hi[i] = *(const bf16x8*)&Bs_hi[wn + i * 16 + lm][kq];
            b_lo[i] = *(const bf16x8*)&Bs_lo[wn + i * 16 + lm][kq];
        }
#pragma unroll
        for (int i = 0; i < 4; i++)
#pragma unroll
            for (int j = 0; j < 4; j++) {
                acc[i][j] = __builtin_amdgcn_mfma_f32_16x16x32_bf16(a_hi[i], b_hi[j], acc[i][j], 0, 0, 0);
                acc[i][j] = __builtin_amdgcn_mfma_f32_16x16x32_bf16(a_lo[i], b_hi[j], acc[i][j], 0, 0, 0);
                acc[i][j] = __builtin_amdgcn_mfma_f32_16x16x32_bf16(a_hi[i], b_lo[j], acc[i][j], 0, 0, 0);
            }
        __syncthreads();
    }

    // epilogue: row = (lane>>4)*4+reg, col = lane&15; scale rows here
    const int rq = (lane >> 4) * 4;
#pragma unroll
    for (int i = 0; i < 4; i++) {
        int mbase = m0 + wm + i * 16 + rq;
#pragma unroll
        for (int rg = 0; rg < 4; rg++) {
            int m = mbase + rg;
            if (m < M) {
                float s = scale[m];
#pragma unroll
                for (int j = 0; j < 4; j++) {
                    int col = wn + j * 16 + lm;
                    uint32_t u = __float_as_uint(acc[i][j][rg] * s);
                    Cout[(size_t)m * 128 + col] =
                        (u16)((u + 0x7FFFu + ((u >> 16) & 1u)) >> 16);
                }
            }
        }
    }
}

#define BF16_LO(u) __uint_as_float((u) << 16)
#define BF16_HI(u) __uint_as_float((u) & 0xFFFF0000u)

// accumulate one bf16x8 (uint4) row-chunk into 8 fp32
#define ADD8(a, u)                                   \
    do {                                             \
        a[0] += BF16_LO((u).x); a[1] += BF16_HI((u).x); \
        a[2] += BF16_LO((u).y); a[3] += BF16_HI((u).y); \
        a[4] += BF16_LO((u).z); a[5] += BF16_HI((u).z); \
        a[6] += BF16_LO((u).w); a[7] += BF16_HI((u).w); \
    } while (0)

// gather core: lane = g*16+c; slot g serves edges e+g / e+4+g; chunk c = 16B of row
__device__ __forceinline__ void gather3(const u16* __restrict__ hb,
                                        const int* __restrict__ row_start,
                                        const int* __restrict__ esrc,
                                        const float* __restrict__ s_in,
                                        int node, int g, int c, int N, int E,
                                        float* __restrict__ tot /*8*/) {
    const uint4* hbase = (const uint4*)hb;
#pragma unroll
    for (int r = 0; r < 3; r++) {
        const int* rs = row_start + (size_t)r * (N + 1);
        const int* es = esrc + (size_t)r * E;
        const uint4* h = hbase + (size_t)r * N * 16 + c;
        int beg = rs[node], end = rs[node + 1];
        float a[8];
#pragma unroll
        for (int j = 0; j < 8; j++) a[j] = 0.f;
        for (int e = beg; e < end; e += 8) {
            int e0 = e + g, e1 = e + 4 + g;
            bool v0 = e0 < end, v1 = e1 < end;
            int i0 = es[v0 ? e0 : beg];
            int i1 = es[v1 ? e1 : beg];
            uint4 u0 = h[(size_t)i0 * 16];
            uint4 u1 = h[(size_t)i1 * 16];
            if (!v0) u0 = make_uint4(0u, 0u, 0u, 0u);
            if (!v1) u1 = make_uint4(0u, 0u, 0u, 0u);
            ADD8(a, u0);
            ADD8(a, u1);
        }
        float w = s_in[(size_t)r * N + node];
#pragma unroll
        for (int j = 0; j < 8; j++) tot[j] += a[j] * w;
    }
    // fold the 4 edge slots: lanes differing in bits 4,5
#pragma unroll
    for (int j = 0; j < 8; j++) {
        tot[j] += __shfl_xor(tot[j], 16);
        tot[j] += __shfl_xor(tot[j], 32);
    }
}

// --- fused gather layer 0: 3 relations + bias + leakyReLU -> acc0 (fp32) ---
__global__ __launch_bounds__(256)
void gather_l0(const u16* __restrict__ hb, const int* __restrict__ row_start,
               const int* __restrict__ esrc, const float* __restrict__ s_in,
               const float* __restrict__ b, float* __restrict__ out, int N, int E) {
    int node = blockIdx.x * 4 + (threadIdx.x >> 6);
    if (node >= N) return;
    int lane = threadIdx.x & 63;
    int g = lane >> 4, c = lane & 15;
    float tot[8];
#pragma unroll
    for (int j = 0; j < 8; j++) tot[j] = 0.f;
    gather3(hb, row_start, esrc, s_in, node, g, c, N, E, tot);
    int cb = c * 8;
#pragma unroll
    for (int j = 0; j < 8; j++) {
        float v = tot[j] + b[cb + j] + b[128 + cb + j] + b[256 + cb + j];
        tot[j] = fmaxf(v, 0.f) + 0.01f * fminf(v, 0.f);
    }
    if (g == 0)
        *(float4*)(out + (size_t)node * 128 + cb) = make_float4(tot[0], tot[1], tot[2], tot[3]);
    else if (g == 1)
        *(float4*)(out + (size_t)node * 128 + cb + 4) = make_float4(tot[4], tot[5], tot[6], tot[7]);
}

// --- fused gather layer 1: 3 relations + bias -> out_h; + logits -----------
__global__ __launch_bounds__(256)
void gather_l1(const u16* __restrict__ hb, const int* __restrict__ row_start,
               const int* __restrict__ esrc, const float* __restrict__ s_in,
               const float* __restrict__ b, const float* __restrict__ fcW,
               const float* __restrict__ fcb, float* __restrict__ out_h,
               float* __restrict__ out_logits, int N, int E) {
    int node = blockIdx.x * 4 + (threadIdx.x >> 6);
    if (node >= N) return;
    int lane = threadIdx.x & 63;
    int g = lane >> 4, c = lane & 15;
    float tot[8];
#pragma unroll
    for (int j = 0; j < 8; j++) tot[j] = 0.f;
    gather3(hb, row_start, esrc, s_in, node, g, c, N, E, tot);
    int cb = c * 8;
#pragma unroll
    for (int j = 0; j < 8; j++)
        tot[j] += b[cb + j] + b[128 + cb + j] + b[256 + cb + j];
    if (g == 0)
        *(float4*)(out_h + (size_t)node * 128 + cb) = make_float4(tot[0], tot[1], tot[2], tot[3]);
    else if (g == 1)
        *(float4*)(out_h + (size_t)node * 128 + cb + 4) = make_float4(tot[4], tot[5], tot[6], tot[7]);

    // logits: slot g owns classes g*4..g*4+3; partial over this lane's 8 channels
    float p0 = 0.f, p1 = 0.f, p2 = 0.f, p3 = 0.f;
#pragma unroll
    for (int j = 0; j < 8; j++) {
        const float* fw = fcW + (size_t)(cb + j) * 16 + g * 4;
        p0 += tot[j] * fw[0];
        p1 += tot[j] * fw[1];
        p2 += tot[j] * fw[2];
        p3 += tot[j] * fw[3];
    }
#pragma unroll
    for (int off = 1; off < 16; off <<= 1) {
        p0 += __shfl_xor(p0, off);
        p1 += __shfl_xor(p1, off);
        p2 += __shfl_xor(p2, off);
        p3 += __shfl_xor(p3, off);
    }
    if (c == 0) {
        int jb = g * 4;
        *(float4*)(out_logits + (size_t)node * 16 + jb) =
            make_float4(p0 + fcb[jb], p1 + fcb[jb + 1], p2 + fcb[jb + 2], p3 + fcb[jb + 3]);
    }
}

extern "C" void kernel_launch(void* const* d_in, const int* in_sizes, int n_in,
                              void* d_out, int out_size, void* d_ws, size_t ws_size,
                              hipStream_t stream) {
    const float* x   = (const float*)d_in[0];
    const int*   src = (const int*)d_in[1];
    const int*   dst = (const int*)d_in[2];
    const float* W0  = (const float*)d_in[3];
    const float* b0  = (const float*)d_in[4];
    const float* W1  = (const float*)d_in[5];
    const float* b1  = (const float*)d_in[6];
    const float* fcW = (const float*)d_in[7];
    const float* fcb = (const float*)d_in[8];

    const int N = in_sizes[0] / 256;   // 100000
    const int E = in_sizes[1] / 3;     // 600000
    const int nb = (N + SCAN_BLK - 1) / SCAN_BLK;

    float* out_h      = (float*)d_out;
    float* out_logits = out_h + (size_t)N * 128;

    char* p = (char*)d_ws;
    auto alloc = [&](size_t bytes) -> char* {
        char* q = p;
        p += (bytes + 255) & ~(size_t)255;
        return q;
    };
    float* s_out     = (float*)alloc(3 * (size_t)N * 4);
    float* s_in      = (float*)alloc(3 * (size_t)N * 4);
    int*   cnt8      = (int*)alloc(2 * 8 * 3 * (size_t)N * 4);
    int*   cnt_out8  = cnt8;
    int*   cnt_in8   = cnt8 + 8 * 3 * (size_t)N;
    int*   cnt_in    = (int*)alloc(3 * (size_t)N * 4);
    int*   row_start = (int*)alloc(3 * (size_t)(N + 1) * 4);
    int*   cursor    = (int*)alloc(3 * (size_t)N * 4);
    int*   bsums     = (int*)alloc(1024 * 4);
    int*   esrc      = (int*)alloc(3 * (size_t)E * 4);
    u16*   w0hi      = (u16*)alloc(3 * 256 * 128 * 2);
    u16*   w0lo      = (u16*)alloc(3 * 256 * 128 * 2);
    u16*   w1hi      = (u16*)alloc(3 * 128 * 128 * 2);
    u16*   w1lo      = (u16*)alloc(3 * 128 * 128 * 2);
    u16*   hb        = (u16*)alloc(3 * (size_t)N * 128 * 2);
    float* acc0      = (float*)alloc((size_t)N * 128 * 4);

    hipMemsetAsync(cnt8, 0, 2 * 8 * 3 * (size_t)N * sizeof(int), stream);

    hist_kernel<<<dim3((E + 255) / 256, 3), 256, 0, stream>>>(src, dst, cnt_out8, cnt_in8, E, N);
    reduce_scales_kernel<<<(3 * N + 255) / 256, 256, 0, stream>>>(
        cnt_out8, cnt_in8, s_out, s_in, cnt_in, 3 * N);

    scan1_kernel<<<dim3(nb, 3), SCAN_T, 0, stream>>>(cnt_in, row_start, bsums, N);
    scan2_kernel<<<1, 1, 0, stream>>>(bsums, row_start, nb, N);
    scan3_kernel<<<dim3(nb, 3), SCAN_T, 0, stream>>>(row_start, bsums, cursor, nb, N);
    bucket_fill_kernel<<<dim3((E + 255) / 256, 3), 256, 0, stream>>>(src, dst, cursor, esrc, E, N);

    prep_w_kernel<<<(3 * 256 * 128 + 3 * 128 * 128 + 255) / 256, 256, 0, stream>>>(
        W0, W1, w0hi, w0lo, w1hi, w1lo);

    int gemm_blocks   = (N + 127) / 128;
    int gather_blocks = (N + 3) / 4;

    gemm_split_bf16<<<dim3(gemm_blocks, 3), 256, 0, stream>>>(
        x, s_out, w0hi, w0lo, hb, N, 256, N);
    gather_l0<<<gather_blocks, 256, 0, stream>>>(hb, row_start, esrc, s_in, b0, acc0, N, E);

    gemm_split_bf16<<<dim3(gemm_blocks, 3), 256, 0, stream>>>(
        acc0, s_out, w1hi, w1lo, hb, N, 128, N);
    gather_l1<<<gather_blocks, 256, 0, stream>>>(hb, row_start, esrc, s_in, b1, fcW, fcb,
                                                 out_h, out_logits, N, E);
}